// Round 11
// baseline (232.442 us; speedup 1.0000x reference)
//
#include <hip/hip_runtime.h>

#define NTOK 8192
#define HDIM 4096
#define NEXP 64
#define CAP  160      // int(8192 * 1.25 / 64)
#define NCAND 192     // screen margin: top-192 fp32 provably contains true top-160
#define KSPLIT 8
#define KPART (HDIM / KSPLIT)   // 512
#define KC   64                 // k per LDS chunk
#define NCH  (KPART / KC)       // 8 chunks

__device__ __forceinline__ unsigned int flip_key(float f) {
    unsigned int u = __float_as_uint(f);
    return u ^ (unsigned int)(((int)u >> 31) | 0x80000000);
}

// ---- Kernel 0: build wf2 (fp32 repacked [k4][e][ksub]) + wt (fp64 [e][k]) ----
// ---- also zero mask + write loss (structurally 0)                          ----
__global__ __launch_bounds__(256) void conv_w(const float* __restrict__ w,
                                              double* __restrict__ wt,
                                              float* __restrict__ wf2,
                                              float* __restrict__ out_mask,
                                              float* __restrict__ out_loss) {
    int i = blockIdx.x * 256 + threadIdx.x;   // grid 1024 -> 262144
    int k = i >> 6, e = i & 63;
    float v = w[i];
    wf2[((size_t)(k >> 2) * NEXP + e) * 4 + (k & 3)] = v;
    wt[(size_t)e * HDIM + k] = (double)v;
    if (i < NTOK * NEXP / 4)
        ((float4*)out_mask)[i] = float4{0.f, 0.f, 0.f, 0.f};
    // loss structurally 0: every expert load == CAP; logf(1.0f + 1e-8f) == 0 in fp32
    if (i == 0) out_loss[0] = 0.0f;
}

// ---- Kernel 1: fp32 screen GEMM (proven gemm_c structure, float accum) ----
// grid 1024 = 128 token-groups x KSPLIT(8). block 512 = 8 waves; wave wv ->
// experts [wv*8, wv*8+8), lanes = tokens tg0..tg0+63. x fp32 in LDS (swizzled).
__global__ __launch_bounds__(512) void gemm_s(const float* __restrict__ x,
                                              const float* __restrict__ wf2,
                                              float* __restrict__ pf) {
    __shared__ float4 xs4[2][64 * 16];   // 2 x 16 KB
    const int tid = threadIdx.x;
    const int l   = tid & 63;
    const int wv  = __builtin_amdgcn_readfirstlane(tid >> 6);  // 0..7, uniform
    const int e0  = wv * 8;
    const int tokgrp = blockIdx.x >> 3;
    const int ks     = blockIdx.x & 7;
    const int tg0    = tokgrp * 64;
    const int kbase  = ks * KPART;

    const float4* x4 = (const float4*)x;

    float acc[8] = {0.f, 0.f, 0.f, 0.f, 0.f, 0.f, 0.f, 0.f};

    // staging: 1024 float4 per chunk, 512 threads -> 2 each
    const int t0s = tid >> 4,          c0s = tid & 15;
    const int t1s = (tid + 512) >> 4,  c1s = tid & 15;
    const int d0  = t0s * 16 + (c0s ^ (t0s & 7));
    const int d1  = t1s * 16 + (c1s ^ (t1s & 7));
    const size_t rs = HDIM / 4;

    xs4[0][d0] = x4[(size_t)(tg0 + t0s) * rs + (kbase >> 2) + c0s];
    xs4[0][d1] = x4[(size_t)(tg0 + t1s) * rs + (kbase >> 2) + c1s];

    for (int ch = 0; ch < NCH; ++ch) {
        __syncthreads();
        const int cur = ch & 1;
        const int k0  = kbase + ch * KC;

        // T14: issue next chunk's global loads BEFORE compute
        float4 r0, r1;
        const bool more = (ch + 1 < NCH);
        if (more) {
            int kn = k0 + KC;
            r0 = x4[(size_t)(tg0 + t0s) * rs + (kn >> 2) + c0s];
            r1 = x4[(size_t)(tg0 + t1s) * rs + (kn >> 2) + c1s];
        }

        #pragma unroll 4
        for (int c4 = 0; c4 < 16; ++c4) {
            float4 f = xs4[cur][l * 16 + (c4 ^ (l & 7))];   // b128
            // 32 contiguous floats (128 B): experts e0..e0+7 x ksub 0..3 (uniform)
            const float* wb = wf2 + ((size_t)((k0 >> 2) + c4) * NEXP + e0) * 4;
            #pragma unroll
            for (int j = 0; j < 8; ++j) {
                acc[j] = fmaf(f.x, wb[j * 4 + 0], acc[j]);
                acc[j] = fmaf(f.y, wb[j * 4 + 1], acc[j]);
                acc[j] = fmaf(f.z, wb[j * 4 + 2], acc[j]);
                acc[j] = fmaf(f.w, wb[j * 4 + 3], acc[j]);
            }
        }

        if (more) {
            xs4[cur ^ 1][d0] = r0;
            xs4[cur ^ 1][d1] = r1;
        }
    }

    #pragma unroll
    for (int j = 0; j < 8; ++j)
        pf[((size_t)ks * NEXP + e0 + j) * NTOK + tg0 + l] = acc[j];
}

// ---- Kernel 2: screen top-NCAND (fp32) -> fp64 rescore -> sort -> top-CAP ----
// 64 blocks (1/expert), 1024 threads = 16 waves. Thread t owns tokens [t*8, t*8+8).
__global__ __launch_bounds__(1024) void topk_rescore(const float* __restrict__ pf,
                                                     const float* __restrict__ x,
                                                     const double* __restrict__ wt,
                                                     float* __restrict__ out_idx,
                                                     float* __restrict__ out_mask) {
    const int e    = blockIdx.x;
    const int tid  = threadIdx.x;
    const int lane = tid & 63;
    const int wv   = tid >> 6;          // 0..15
    const size_t S = (size_t)NEXP * NTOK;

    // ---- screen values: sum 8 fp32 K-split partials, 8 tokens per thread ----
    unsigned int k8[8];
    {
        float a[8] = {0.f, 0.f, 0.f, 0.f, 0.f, 0.f, 0.f, 0.f};
        #pragma unroll
        for (int s = 0; s < KSPLIT; ++s) {
            const float4* pr = (const float4*)(pf + (size_t)s * S + (size_t)e * NTOK) + tid * 2;
            float4 u = pr[0], v = pr[1];
            a[0] += u.x; a[1] += u.y; a[2] += u.z; a[3] += u.w;
            a[4] += v.x; a[5] += v.y; a[6] += v.z; a[7] += v.w;
        }
        #pragma unroll
        for (int j = 0; j < 8; ++j) k8[j] = flip_key(a[j]);
    }

    // ---- bisection: pth = NCAND-th largest screen key ----
    __shared__ int scnt[16];
    unsigned int pth = 0;
    for (int b = 31; b >= 0; --b) {
        unsigned int cand = pth | (1u << b);
        int cl = 0;
        #pragma unroll
        for (int j = 0; j < 8; ++j) cl += (k8[j] >= cand);
        #pragma unroll
        for (int off = 32; off > 0; off >>= 1) cl += __shfl_xor(cl, off);
        if (lane == 0) scnt[wv] = cl;
        __syncthreads();
        int c = 0;
        #pragma unroll
        for (int q = 0; q < 16; ++q) c += scnt[q];
        if (c >= NCAND) pth = cand;
        __syncthreads();
    }

    // ---- candidate list (order arbitrary; n in [NCAND, NCAND+ties] <= 256) ----
    __shared__ int clist[256];
    __shared__ int cnum;
    if (tid == 0) cnum = 0;
    __syncthreads();
    #pragma unroll
    for (int j = 0; j < 8; ++j)
        if (k8[j] >= pth) {
            int pos = atomicAdd(&cnum, 1);
            if (pos < 256) clist[pos] = tid * 8 + j;
        }
    __syncthreads();
    const int n = cnum < 256 ? cnum : 256;

    // ---- fp64 rescore: wave per candidate (strided), 64-lane K split ----
    __shared__ unsigned long long sk[256];
    if (tid < 256) sk[tid] = 0ULL;
    __syncthreads();
    for (int c = wv; c < n; c += 16) {
        const int tok = clist[c];
        const float*  xr = x  + (size_t)tok * HDIM;
        const double* wr = wt + (size_t)e   * HDIM;
        double s0 = 0.0, s1 = 0.0, s2 = 0.0, s3 = 0.0;
        #pragma unroll 4
        for (int i = 0; i < 16; ++i) {
            int k = i * 256 + lane;
            s0 = fma((double)xr[k],       wr[k],       s0);
            s1 = fma((double)xr[k + 64],  wr[k + 64],  s1);
            s2 = fma((double)xr[k + 128], wr[k + 128], s2);
            s3 = fma((double)xr[k + 192], wr[k + 192], s3);
        }
        double s = (s0 + s1) + (s2 + s3);
        #pragma unroll
        for (int off = 32; off > 0; off >>= 1)
            s += __shfl_xor(s, off);
        if (lane == 0)
            sk[c] = ((unsigned long long)flip_key((float)s) << 13) | (unsigned int)(8191 - tok);
    }
    __syncthreads();

    // ---- bitonic sort 256 desc (key desc, tie -> smaller token first) ----
    for (int size = 2; size <= 256; size <<= 1) {
        for (int stride = size >> 1; stride > 0; stride >>= 1) {
            if (tid < 256) {
                int i = tid, jj = i ^ stride;
                if (jj > i) {
                    unsigned long long a = sk[i], b2 = sk[jj];
                    bool desc = ((i & size) == 0);
                    if (desc ? (a < b2) : (a > b2)) { sk[i] = b2; sk[jj] = a; }
                }
            }
            __syncthreads();
        }
    }

    if (tid < CAP) {
        int tok = 8191 - (int)(sk[tid] & 0x1FFFULL);
        out_idx[e * CAP + tid] = (float)tok;
        out_mask[(size_t)tok * NEXP + e] = 1.0f;
    }
}

extern "C" void kernel_launch(void* const* d_in, const int* in_sizes, int n_in,
                              void* d_out, int out_size, void* d_ws, size_t ws_size,
                              hipStream_t stream) {
    const float* x = (const float*)d_in[0];
    const float* w = (const float*)d_in[1];

    float* out      = (float*)d_out;
    float* out_idx  = out;                            // [64][160]
    float* out_mask = out + NEXP * CAP;               // [8192][64]
    float* out_loss = out + NEXP * CAP + NTOK * NEXP; // [1]

    double* wt  = (double*)d_ws;                      // 2 MB fp64 w^T [e][k]
    float*  wf2 = (float*)(wt + (size_t)NEXP * HDIM); // 1 MB fp32 repacked w
    float*  pf  = wf2 + (size_t)HDIM * NEXP;          // 16 MB fp32 partials [8][64][8192]

    conv_w<<<HDIM * NEXP / 256, 256, 0, stream>>>(w, wt, wf2, out_mask, out_loss);
    gemm_s<<<1024, 512, 0, stream>>>(x, wf2, pf);
    topk_rescore<<<NEXP, 1024, 0, stream>>>(pf, x, wt, out_idx, out_mask);
}

// Round 12
// 118.172 us; speedup vs baseline: 1.9670x; 1.9670x over previous
//
#include <hip/hip_runtime.h>

#define NTOK 8192
#define HDIM 4096
#define NEXP 64
#define CAP   160     // int(8192 * 1.25 / 64)
#define NCAND 256     // bf16-screen margin: 60 sigma vs rank-160/256 gap
#define KSPLIT 4
#define KPART (HDIM / KSPLIT)   // 1024
#define NCH   (KPART / 128)     // 8 chunks of 128 k

typedef float  f32x4 __attribute__((ext_vector_type(4)));
typedef short  s16x8 __attribute__((ext_vector_type(8)));

__device__ __forceinline__ unsigned int flip_key(float f) {
    unsigned int u = __float_as_uint(f);
    return u ^ (unsigned int)(((int)u >> 31) | 0x80000000);
}
__device__ __forceinline__ unsigned short f2bf(float f) {   // RNE truncation
    unsigned int u = __float_as_uint(f);
    return (unsigned short)((u + 0x7FFFu + ((u >> 16) & 1u)) >> 16);
}

// ---- Kernel 0: build wt (fp64 [e][k]) + wfrag (bf16 B-fragments) + mask/loss ----
// wfrag[nt][kc][lane][j] = w[kc*32 + 8*(lane>>4) + j][nt*16 + (lane&15)]
__global__ __launch_bounds__(256) void conv_w(const float* __restrict__ w,
                                              double* __restrict__ wt,
                                              unsigned short* __restrict__ wfrag,
                                              float* __restrict__ out_mask,
                                              float* __restrict__ out_loss) {
    int i = blockIdx.x * 256 + threadIdx.x;   // grid 1024 -> 262144
    int k = i >> 6, e = i & 63;
    wt[(size_t)e * HDIM + k] = (double)w[i];
    if (i < 4 * 128 * 64) {                   // 32768 fragment entries
        int l  = i & 63;
        int kc = (i >> 6) & 127;
        int nt = i >> 13;
        int eb = nt * 16 + (l & 15);
        int kb = kc * 32 + 8 * (l >> 4);
        #pragma unroll
        for (int j = 0; j < 8; ++j)
            wfrag[(size_t)i * 8 + j] = f2bf(w[(size_t)(kb + j) * NEXP + eb]);
    }
    if (i < NTOK * NEXP / 4)
        ((float4*)out_mask)[i] = float4{0.f, 0.f, 0.f, 0.f};
    // loss structurally 0: every expert load == CAP; logf(1.0f + 1e-8f) == 0 in fp32
    if (i == 0) out_loss[0] = 0.0f;
}

// ---- Kernel 1: bf16 MFMA screen GEMM -> pf[ks][e][tok] fp32 ----
// grid 512 = 128 token-groups x KSPLIT(4). block 512 = 8 waves.
// wave wv: m-tile = wv>>1 (16 tokens), n-tiles = (wv&1)*2 + {0,1} (2 x 16 experts).
__global__ __launch_bounds__(512) void screen_mfma(const float* __restrict__ x,
                                                   const unsigned short* __restrict__ wfrag,
                                                   float* __restrict__ pf) {
    __shared__ unsigned short lx[2][64 * 128];   // 2 x 16 KB bf16 [tok][k], XOR-swizzled
    const int tid = threadIdx.x;
    const int l   = tid & 63;
    const int wv  = __builtin_amdgcn_readfirstlane(tid >> 6);
    const int mt  = wv >> 1;
    const int nb  = (wv & 1) * 2;
    const int tokgrp = blockIdx.x >> 2;
    const int ks     = blockIdx.x & 3;
    const int tok0   = tokgrp * 64;
    const int kbase  = ks * KPART;

    const float4* x4 = (const float4*)x;
    const size_t rs = HDIM / 4;

    // staging: thread -> row t, k-segment seg (16 floats)
    const int t   = tid >> 3;
    const int seg = tid & 7;
    const int swz = (t & 7) << 3;   // element-unit swizzle (16 B granules)

    f32x4 acc0 = {0.f, 0.f, 0.f, 0.f}, acc1 = {0.f, 0.f, 0.f, 0.f};

    // prologue: stage chunk 0
    {
        const float4* xr = x4 + (size_t)(tok0 + t) * rs + (kbase >> 2) + seg * 4;
        float4 a = xr[0], b = xr[1], c = xr[2], d = xr[3];
        unsigned short u[16];
        u[0]=f2bf(a.x); u[1]=f2bf(a.y); u[2]=f2bf(a.z); u[3]=f2bf(a.w);
        u[4]=f2bf(b.x); u[5]=f2bf(b.y); u[6]=f2bf(b.z); u[7]=f2bf(b.w);
        u[8]=f2bf(c.x); u[9]=f2bf(c.y); u[10]=f2bf(c.z); u[11]=f2bf(c.w);
        u[12]=f2bf(d.x); u[13]=f2bf(d.y); u[14]=f2bf(d.z); u[15]=f2bf(d.w);
        *(s16x8*)&lx[0][t * 128 + ((seg * 16)     ^ swz)] = *(s16x8*)&u[0];
        *(s16x8*)&lx[0][t * 128 + ((seg * 16 + 8) ^ swz)] = *(s16x8*)&u[8];
    }

    for (int ch = 0; ch < NCH; ++ch) {
        __syncthreads();
        const int cur = ch & 1;

        float4 a, b, c, d;
        const bool more = (ch + 1 < NCH);
        if (more) {   // T14: issue next chunk's loads before compute
            const float4* xr = x4 + (size_t)(tok0 + t) * rs + ((kbase + (ch + 1) * 128) >> 2) + seg * 4;
            a = xr[0]; b = xr[1]; c = xr[2]; d = xr[3];
        }

        const int row  = mt * 16 + (l & 15);
        const int rswz = (row & 7) << 3;
        #pragma unroll
        for (int kk = 0; kk < 4; ++kk) {
            s16x8 af = *(const s16x8*)&lx[cur][row * 128 + ((kk * 32 + 8 * (l >> 4)) ^ rswz)];
            int kc = ks * 32 + ch * 4 + kk;   // global k32 index
            s16x8 bf0 = *(const s16x8*)&wfrag[(((size_t)(nb    ) * 128 + kc) * 64 + l) * 8];
            s16x8 bf1 = *(const s16x8*)&wfrag[(((size_t)(nb + 1) * 128 + kc) * 64 + l) * 8];
            acc0 = __builtin_amdgcn_mfma_f32_16x16x32_bf16(af, bf0, acc0, 0, 0, 0);
            acc1 = __builtin_amdgcn_mfma_f32_16x16x32_bf16(af, bf1, acc1, 0, 0, 0);
        }

        if (more) {
            unsigned short u[16];
            u[0]=f2bf(a.x); u[1]=f2bf(a.y); u[2]=f2bf(a.z); u[3]=f2bf(a.w);
            u[4]=f2bf(b.x); u[5]=f2bf(b.y); u[6]=f2bf(b.z); u[7]=f2bf(b.w);
            u[8]=f2bf(c.x); u[9]=f2bf(c.y); u[10]=f2bf(c.z); u[11]=f2bf(c.w);
            u[12]=f2bf(d.x); u[13]=f2bf(d.y); u[14]=f2bf(d.z); u[15]=f2bf(d.w);
            *(s16x8*)&lx[cur ^ 1][t * 128 + ((seg * 16)     ^ swz)] = *(s16x8*)&u[0];
            *(s16x8*)&lx[cur ^ 1][t * 128 + ((seg * 16 + 8) ^ swz)] = *(s16x8*)&u[8];
        }
    }

    // store: D row = (l>>4)*4 + reg (token-sub), col = l&15 (expert-sub)  [m89]
    {
        const int tokw = tok0 + mt * 16 + (l >> 4) * 4;
        float* p0 = pf + ((size_t)ks * NEXP + nb * 16 + (l & 15)) * NTOK + tokw;
        float* p1 = pf + ((size_t)ks * NEXP + (nb + 1) * 16 + (l & 15)) * NTOK + tokw;
        #pragma unroll
        for (int r = 0; r < 4; ++r) { p0[r] = acc0[r]; p1[r] = acc1[r]; }
    }
}

// ---- Kernel 2: per-expert screen top-NCAND -> candidate list ----
// 64 blocks, 1024 threads; thread owns 8 tokens.
__global__ __launch_bounds__(1024) void screen_select(const float* __restrict__ pf,
                                                      int* __restrict__ clist,
                                                      unsigned long long* __restrict__ skall) {
    const int e    = blockIdx.x;
    const int tid  = threadIdx.x;
    const int lane = tid & 63;
    const int wv   = tid >> 6;
    const size_t S = (size_t)NEXP * NTOK;

    if (tid < NCAND) { clist[e * NCAND + tid] = -1; skall[e * NCAND + tid] = 0ULL; }

    unsigned int k8[8];
    {
        float a[8] = {0.f,0.f,0.f,0.f,0.f,0.f,0.f,0.f};
        #pragma unroll
        for (int s = 0; s < KSPLIT; ++s) {
            const float4* pr = (const float4*)(pf + (size_t)s * S + (size_t)e * NTOK) + tid * 2;
            float4 u = pr[0], v = pr[1];
            a[0]+=u.x; a[1]+=u.y; a[2]+=u.z; a[3]+=u.w;
            a[4]+=v.x; a[5]+=v.y; a[6]+=v.z; a[7]+=v.w;
        }
        #pragma unroll
        for (int j = 0; j < 8; ++j) k8[j] = flip_key(a[j]);
    }

    __shared__ int scnt[16];
    unsigned int pth = 0;
    for (int b = 31; b >= 0; --b) {
        unsigned int cand = pth | (1u << b);
        int cl = 0;
        #pragma unroll
        for (int j = 0; j < 8; ++j) cl += (k8[j] >= cand);
        #pragma unroll
        for (int off = 32; off > 0; off >>= 1) cl += __shfl_xor(cl, off);
        if (lane == 0) scnt[wv] = cl;
        __syncthreads();
        int c = 0;
        #pragma unroll
        for (int q = 0; q < 16; ++q) c += scnt[q];
        if (c >= NCAND) pth = cand;
        __syncthreads();
    }

    __shared__ int cnum;
    if (tid == 0) cnum = 0;
    __syncthreads();
    #pragma unroll
    for (int j = 0; j < 8; ++j)
        if (k8[j] >= pth) {
            int pos = atomicAdd(&cnum, 1);
            if (pos < NCAND) clist[e * NCAND + pos] = tid * 8 + j;
        }
}

// ---- Kernel 3: fp64 rescore, one wave-iteration per candidate (proven math) ----
// grid 256 = 64 experts x 4 quarters; block 512 = 8 waves; each wave 8 candidates.
__global__ __launch_bounds__(512) void rescore(const int* __restrict__ clist,
                                               const float* __restrict__ x,
                                               const double* __restrict__ wt,
                                               unsigned long long* __restrict__ skall) {
    const int e    = blockIdx.x >> 2;
    const int quad = blockIdx.x & 3;
    const int lane = threadIdx.x & 63;
    const int wv   = threadIdx.x >> 6;
    const double* wr = wt + (size_t)e * HDIM;

    #pragma unroll
    for (int i = 0; i < 8; ++i) {
        const int ci  = quad * 64 + wv * 8 + i;
        const int tok = clist[e * NCAND + ci];
        if (tok < 0) continue;
        const float* xr = x + (size_t)tok * HDIM;
        double s0 = 0.0, s1 = 0.0, s2 = 0.0, s3 = 0.0;
        #pragma unroll 4
        for (int q = 0; q < 16; ++q) {
            int k = q * 256 + lane;
            s0 = fma((double)xr[k],       wr[k],       s0);
            s1 = fma((double)xr[k + 64],  wr[k + 64],  s1);
            s2 = fma((double)xr[k + 128], wr[k + 128], s2);
            s3 = fma((double)xr[k + 192], wr[k + 192], s3);
        }
        double s = (s0 + s1) + (s2 + s3);
        #pragma unroll
        for (int off = 32; off > 0; off >>= 1)
            s += __shfl_xor(s, off);
        if (lane == 0)
            skall[e * NCAND + ci] =
                ((unsigned long long)flip_key((float)s) << 13) | (unsigned int)(8191 - tok);
    }
}

// ---- Kernel 4: final bitonic sort (proven) + emit idx/mask ----
__global__ __launch_bounds__(256) void final_sort(const unsigned long long* __restrict__ skall,
                                                  float* __restrict__ out_idx,
                                                  float* __restrict__ out_mask) {
    const int e   = blockIdx.x;
    const int tid = threadIdx.x;
    __shared__ unsigned long long sk[256];
    sk[tid] = skall[e * NCAND + tid];
    __syncthreads();

    for (int size = 2; size <= 256; size <<= 1) {
        for (int stride = size >> 1; stride > 0; stride >>= 1) {
            int i = tid, jj = i ^ stride;
            if (jj > i) {
                unsigned long long a = sk[i], b2 = sk[jj];
                bool desc = ((i & size) == 0);
                if (desc ? (a < b2) : (a > b2)) { sk[i] = b2; sk[jj] = a; }
            }
            __syncthreads();
        }
    }

    if (tid < CAP) {
        int tok = 8191 - (int)(sk[tid] & 0x1FFFULL);
        out_idx[e * CAP + tid] = (float)tok;
        out_mask[(size_t)tok * NEXP + e] = 1.0f;
    }
}

extern "C" void kernel_launch(void* const* d_in, const int* in_sizes, int n_in,
                              void* d_out, int out_size, void* d_ws, size_t ws_size,
                              hipStream_t stream) {
    const float* x = (const float*)d_in[0];
    const float* w = (const float*)d_in[1];

    float* out      = (float*)d_out;
    float* out_idx  = out;                            // [64][160]
    float* out_mask = out + NEXP * CAP;               // [8192][64]
    float* out_loss = out + NEXP * CAP + NTOK * NEXP; // [1]

    double*             wt    = (double*)d_ws;                          // 2 MB
    unsigned short*     wfrag = (unsigned short*)(wt + (size_t)NEXP * HDIM);   // 512 KB
    float*              pf    = (float*)(wfrag + (size_t)4 * 128 * 64 * 8);    // 8 MB
    int*                clist = (int*)(pf + (size_t)KSPLIT * NEXP * NTOK);     // 64 KB
    unsigned long long* skall = (unsigned long long*)(clist + NEXP * NCAND);   // 128 KB

    conv_w<<<HDIM * NEXP / 256, 256, 0, stream>>>(w, wt, wfrag, out_mask, out_loss);
    screen_mfma<<<512, 512, 0, stream>>>(x, wfrag, pf);
    screen_select<<<NEXP, 1024, 0, stream>>>(pf, clist, skall);
    rescore<<<256, 512, 0, stream>>>(clist, x, wt, skall);
    final_sort<<<NEXP, 256, 0, stream>>>(skall, out_idx, out_mask);
}